// Round 8
// baseline (33.110 us; speedup 1.0000x reference)
//
#include <hip/hip_runtime.h>

// messages: [B=64, E=4096, D=128] f32 ; tgt: [B,E] int32 in [0,N=512)
// out: [B, N, D] f32 segment-sum.
// Fused kernel: block owns (batch b, 64 output rows). Single-pass LDS bucket
// binning, then dual-seg gather: 2 segs interleaved per wave iteration ->
// 16 independent 512B loads in flight (halves waitcnt-drain count vs R7).
constexpr int B = 64, E = 4096, N = 512, D = 128;
constexpr int QN = 64;                 // segs owned per block
constexpr int CAP = 32;                // bucket slots per seg (lambda=8)
constexpr int OVF = 256;               // overflow list capacity (~never hit)
constexpr int THREADS = 512;           // 8 waves
constexpr int EPT = E / THREADS;       // 8 targets scanned per thread
constexpr int NBLK = B * (N / QN);     // 512 blocks

__global__ __launch_bounds__(THREADS)
void fused_seg_sum(const float* __restrict__ msgs,
                   const int* __restrict__ tgt,
                   float* __restrict__ out) {
    __shared__ int cnt[QN];                   // per-seg cursors
    __shared__ unsigned short lst[QN * CAP];  // fixed-slot buckets (4 KiB)
    __shared__ int novf;
    __shared__ unsigned int ovf[OVF];         // (n<<12)|e overflow entries

    const int tid  = threadIdx.x;
    const int lane = tid & 63;
    const int w    = tid >> 6;            // wave 0..7
    const int b    = blockIdx.x >> 3;     // 8 blocks per batch
    const int n0   = (blockIdx.x & 7) * QN;

    if (tid < QN) cnt[tid] = 0;
    if (tid == THREADS - 1) novf = 0;
    __syncthreads();

    // ---- single-pass binning: 1 LDS atomic + 1 LDS write per match ----
    const int* tb = tgt + b * E;
    #pragma unroll
    for (int t = 0; t < EPT; ++t) {
        const int n = tb[t * THREADS + tid] - n0;       // coalesced idx read
        if ((unsigned)n < (unsigned)QN) {
            const int e = t * THREADS + tid;
            const int slot = atomicAdd(&cnt[n], 1);
            if (slot < CAP) lst[n * CAP + slot] = (unsigned short)e;
            else {                                       // ~never taken
                const int o = atomicAdd(&novf, 1);
                if (o < OVF) ovf[o] = ((unsigned)n << 12) | (unsigned)e;
            }
        }
    }
    __syncthreads();

    // ---- gather: wave w owns segs n0+w*8 .. +7, two at a time ----
    const float2* mb = reinterpret_cast<const float2*>(msgs) + (size_t)b * E * 64;
    float2* ob = reinterpret_cast<float2*>(out) + ((size_t)b * N + n0) * 64;
    const int no = novf;                  // wave-uniform (post-barrier)

    #pragma unroll
    for (int p = 0; p < 4; ++p) {
        const int nA = w * 8 + 2 * p;
        const int nB = nA + 1;
        const int kA = min(cnt[nA], CAP);
        const int kB = min(cnt[nB], CAP);
        float axA = 0.f, ayA = 0.f, axB = 0.f, ayB = 0.f;
        const int kmax = max(kA, kB);

        for (int i = 0; i < kmax; i += 8) {
            int eA[8], eB[8]; float wA[8], wB[8];
            #pragma unroll
            for (int j = 0; j < 8; ++j) {               // LDS broadcast ids
                const bool vA = (i + j < kA), vB = (i + j < kB);
                eA[j] = vA ? (int)lst[nA * CAP + i + j] : 0;
                wA[j] = vA ? 1.f : 0.f;
                eB[j] = vB ? (int)lst[nB * CAP + i + j] : 0;
                wB[j] = vB ? 1.f : 0.f;
            }
            float2 vA2[8], vB2[8];
            #pragma unroll
            for (int j = 0; j < 8; ++j)                  // 16 independent
                vA2[j] = mb[(size_t)eA[j] * 64 + lane];  // 512B loads
            #pragma unroll
            for (int j = 0; j < 8; ++j)                  // in flight
                vB2[j] = mb[(size_t)eB[j] * 64 + lane];
            #pragma unroll
            for (int j = 0; j < 8; ++j) {
                axA += wA[j] * vA2[j].x; ayA += wA[j] * vA2[j].y;
                axB += wB[j] * vB2[j].x; ayB += wB[j] * vB2[j].y;
            }
        }
        if (no) {                                   // overflow safety net
            for (int o = 0; o < no && o < OVF; ++o) {
                const unsigned v = ovf[o];
                const int n = (int)(v >> 12);
                if (n == nA || n == nB) {
                    const float2 r = mb[(size_t)(v & 0xFFFu) * 64 + lane];
                    if (n == nA) { axA += r.x; ayA += r.y; }
                    else         { axB += r.x; ayB += r.y; }
                }
            }
        }
        float2 rA; rA.x = axA; rA.y = ayA;
        float2 rB; rB.x = axB; rB.y = ayB;
        ob[(size_t)nA * 64 + lane] = rA;            // covers every output once
        ob[(size_t)nB * 64 + lane] = rB;
    }
}

extern "C" void kernel_launch(void* const* d_in, const int* in_sizes, int n_in,
                              void* d_out, int out_size, void* d_ws, size_t ws_size,
                              hipStream_t stream) {
    const float* msgs = (const float*)d_in[0];
    const int*   tgt  = (const int*)d_in[1];
    float* out = (float*)d_out;
    fused_seg_sum<<<NBLK, THREADS, 0, stream>>>(msgs, tgt, out);
}